// Round 17
// baseline (111.927 us; speedup 1.0000x reference)
//
#include <hip/hip_runtime.h>

// PatcherUnfold: y[b,l,e] = sum_k patches[b,l,k] * W[e,k] + bias[e]
// Implicit GEMM, M=36864 N=768 K=768, bf16 MFMA 16x16x32, fp32 accum.
// Round 17: zero-LDS zero-barrier dataflow (R15) + EXPLICIT 2-stage register
// pipeline (R15 failed because hipcc didn't auto-pipeline: VGPR=80).
// Per iteration: issue stage-N+1 loads -> 24 MFMA on stage N -> cvt N+1.
// Named stage registers (arA/arB, brA/brB, pfA/pfB) — rule #20, all
// compile-time indexed. No __shared__, no __syncthreads.

namespace {

constexpr int PB   = 16;
constexpr int Cch  = 3;
constexpr int Him  = 384;
constexpr int Wim  = 384;
constexpr int GWp  = 24;
constexpr int Lp   = 576;
constexpr int Kd   = 768;
constexpr int Nd   = 768;
constexpr int Md   = 64 * Lp;        // 36864
constexpr int BM   = 64;
constexpr int BN   = 384;            // 4 waves x 96 cols
constexpr int GN   = Nd / BN;        // 2
constexpr int NBLK = (Md / BM) * GN; // 1152 = 8 * 144
constexpr int NKC  = Kd / 32;        // 24 K-chunks of 32

typedef __bf16 bf16x8 __attribute__((ext_vector_type(8)));
typedef float  f32x4  __attribute__((ext_vector_type(4)));

// Pack W[768][768] fp32 -> fragment-ordered bf16 (R9-proven):
// fragment (g, kc): 64 lanes x 8 bf16 contiguous (1024 B); lane l holds
// W[g*16 + (l&15)][kc*32 + (l>>4)*8 .. +8].
__global__ __launch_bounds__(256)
void pack_w(const float* __restrict__ Wm, __bf16* __restrict__ Wf)
{
    const int gid  = blockIdx.x * 256 + threadIdx.x;  // 0..73727
    const int frag = gid >> 6;
    const int lane = gid & 63;
    const int g    = frag / NKC;
    const int kc   = frag - g * NKC;
    const float* src = Wm + (g * 16 + (lane & 15)) * Kd + kc * 32 + (lane >> 4) * 8;
    const f32x4 v0 = *(const f32x4*)src;
    const f32x4 v1 = *(const f32x4*)(src + 4);
    bf16x8 h;
    #pragma unroll
    for (int e = 0; e < 4; ++e) { h[e] = (__bf16)v0[e]; h[4 + e] = (__bf16)v1[e]; }
    *(bf16x8*)(Wf + (size_t)gid * 8) = h;
}

__global__ __launch_bounds__(256, 2)
void patch_embed_gemm(const float* __restrict__ x,
                      const __bf16* __restrict__ Wf,
                      const float* __restrict__ bias,
                      float* __restrict__ out)
{
    // XCD-chunked swizzle (1152 % 8 == 0 -> bijective), bm-major.
    const int h  = blockIdx.x;
    const int l  = (h & 7) * (NBLK / 8) + (h >> 3);
    const int bm = l >> 1;
    const int bn = l & 1;

    const int tid  = threadIdx.x;
    const int lane = tid & 63;
    const int wc   = tid >> 6;   // 0..3 -> 96-col strip
    const int fr   = lane & 15;
    const int kg   = lane >> 4;

    // ---- A fragment row-base pointers (K-invariant, R15-verified):
    // lane fragment for chunk kc = x[b][kc>>3][gy*16 + (kc&7)*2 + (kg>>1)]
    //                               [gx*16 + (kg&1)*8 .. +8]
    const float* abase[4];
    #pragma unroll
    for (int fi = 0; fi < 4; ++fi) {
        const int m  = bm * BM + fi * 16 + fr;
        const int b  = m / Lp;
        const int li = m - b * Lp;
        const int gy = li / GWp;
        const int gx = li - gy * GWp;
        abase[fi] = x + (size_t)b * (Cch * Him * Wim)
                      + (gy * PB + (kg >> 1)) * Wim + gx * PB + (kg & 1) * 8;
    }

    // ---- B fragment base: col-groups g = bn*24 + wc*6 + fj, chunk kc
    const __bf16* const wfw = Wf + (size_t)(bn * 24 + wc * 6) * NKC * 512 + lane * 8;

    f32x4 acc[4][6];
    #pragma unroll
    for (int i = 0; i < 4; ++i)
        #pragma unroll
        for (int j = 0; j < 6; ++j)
            acc[i][j] = f32x4{0.f, 0.f, 0.f, 0.f};

    // ---- named pipeline stages (rule #20: all indices compile-time) ----
    f32x4  pfA[8], pfB[8];           // raw A floats in flight
    bf16x8 arA[4], arB[4];           // converted A fragments
    bf16x8 brA[6], brB[6];           // B fragments (bf16, no cvt needed)

    auto issue = [&](f32x4 (&pf)[8], bf16x8 (&br)[6], int kc) {
        const int aoff = (kc >> 3) * (Him * Wim) + (kc & 7) * 2 * Wim;
        #pragma unroll
        for (int fi = 0; fi < 4; ++fi) {
            pf[2 * fi]     = *(const f32x4*)(abase[fi] + aoff);
            pf[2 * fi + 1] = *(const f32x4*)(abase[fi] + aoff + 4);
        }
        const __bf16* wp = wfw + kc * 512;
        #pragma unroll
        for (int fj = 0; fj < 6; ++fj)
            br[fj] = *(const bf16x8*)(wp + fj * (NKC * 512));
    };

    auto docvt = [&](const f32x4 (&pf)[8], bf16x8 (&ar)[4]) {
        #pragma unroll
        for (int fi = 0; fi < 4; ++fi) {
            bf16x8 t;
            #pragma unroll
            for (int e = 0; e < 4; ++e) {
                t[e]     = (__bf16)pf[2 * fi][e];
                t[4 + e] = (__bf16)pf[2 * fi + 1][e];
            }
            ar[fi] = t;
        }
    };

    auto mma = [&](const bf16x8 (&ar)[4], const bf16x8 (&br)[6]) {
        #pragma unroll
        for (int fi = 0; fi < 4; ++fi)
            #pragma unroll
            for (int fj = 0; fj < 6; ++fj)
                acc[fi][fj] = __builtin_amdgcn_mfma_f32_16x16x32_bf16(
                    ar[fi], br[fj], acc[fi][fj], 0, 0, 0);
    };

    // ---- prologue: stage 0 ----
    issue(pfA, brA, 0);
    docvt(pfA, arA);                 // one exposed latency, once per block

    // ---- main loop: 2 chunks per iteration, fully static ----
    for (int kc = 0; kc < NKC; kc += 2) {
        issue(pfB, brB, kc + 1);     // in flight under mma(A)
        mma(arA, brA);
        if (kc + 2 < NKC) issue(pfA, brA, kc + 2);  // brA free after mma(A)
        docvt(pfB, arB);             // vmcnt: covered by mma(A)+issue(A)
        mma(arB, brB);
        if (kc + 2 < NKC) docvt(pfA, arA);          // covered by mma(B)
    }

    // epilogue: C/D layout col = lane&15, row = (lane>>4)*4 + j
    const int orow0 = bm * BM;
    const int ocol0 = bn * BN + wc * 96;
    #pragma unroll
    for (int fj = 0; fj < 6; ++fj) {
        const int col = ocol0 + fj * 16 + fr;
        const float bv = bias[col];
        #pragma unroll
        for (int fi = 0; fi < 4; ++fi) {
            const int row = orow0 + fi * 16 + kg * 4;
            #pragma unroll
            for (int j = 0; j < 4; ++j)
                out[(row + j) * Nd + col] = acc[fi][fj][j] + bv;
        }
    }
}

} // namespace

extern "C" void kernel_launch(void* const* d_in, const int* in_sizes, int n_in,
                              void* d_out, int out_size, void* d_ws, size_t ws_size,
                              hipStream_t stream)
{
    (void)in_sizes; (void)n_in; (void)out_size; (void)ws_size;
    const float* x  = (const float*)d_in[0];
    const float* Wm = (const float*)d_in[1];
    const float* bs = (const float*)d_in[2];
    float* outp = (float*)d_out;
    __bf16* Wf = (__bf16*)d_ws;   // 768*768*2 B, fragment-ordered

    pack_w<<<dim3(Kd * Nd / (256 * 8)), dim3(256), 0, stream>>>(Wm, Wf);
    patch_embed_gemm<<<dim3(NBLK), dim3(256), 0, stream>>>(x, Wf, bs, outp);
}

// Round 18
// 71.299 us; speedup vs baseline: 1.5698x; 1.5698x over previous
//
#include <hip/hip_runtime.h>

// PatcherUnfold: y[b,l,e] = sum_k patches[b,l,k] * W[e,k] + bias[e]
// Implicit GEMM, M=36864 N=768 K=768, bf16 MFMA 16x16x32, fp32 accum.
// FINAL (= Round 10 / Round 16, session best 70.8-72.2 us, ~614 TF eff):
//  - block 64x384, 4 waves (1x4), wave tile 64x96, GN=2 (min x re-read)
//  - W pre-packed to MFMA-fragment order in d_ws; B fragments loaded
//    straight from L2 (1024 B coalesced per fragment), never staged in LDS
//  - A reg-staged fp32->bf16 into a single 8 KiB LDS buffer, 128-B rows,
//    XOR swizzle byte^=(row&7)<<4 (0 bank conflicts measured)
//  - 2 barriers/K-step, x loads for t+1 issued under compute(t)
//  - XCD-chunked bijective block swizzle (1152 = 8*144, bm-major)
// Session ledger (all regressed vs this): 4-phase derived-wait (R5 -12%),
// 1-barrier dbuf (R11 -35%), B reg-dbuf (R12 -5%), 2x occupancy (R13 -6%),
// B-hoist+setprio (R14 -7%), zero-LDS dataflow (R15 -65%), explicit
// reg-pipeline dataflow (R17 -58%, compiler sank the prefetch: VGPR=104).

namespace {

constexpr int PB   = 16;
constexpr int Cch  = 3;
constexpr int Him  = 384;
constexpr int Wim  = 384;
constexpr int GWp  = 24;
constexpr int Lp   = 576;
constexpr int Kd   = 768;
constexpr int Nd   = 768;
constexpr int Md   = 64 * Lp;        // 36864
constexpr int BM   = 64;
constexpr int BN   = 384;
constexpr int BK   = 64;
constexpr int NT   = Kd / BK;        // 12
constexpr int GN   = Nd / BN;        // 2
constexpr int NBLK = (Md / BM) * GN; // 1152 = 8 * 144
constexpr int NKC  = Kd / 32;        // 24 k-chunks per 16-col group

typedef __bf16 bf16x4 __attribute__((ext_vector_type(4)));
typedef __bf16 bf16x8 __attribute__((ext_vector_type(8)));
typedef float  f32x4  __attribute__((ext_vector_type(4)));

// Pack W[768][768] fp32 -> fragment-ordered bf16:
// fragment (g, kc): 64 lanes x 8 bf16 contiguous (1024 B); lane l holds
// W[g*16 + (l&15)][kc*32 + (l>>4)*8 .. +8].
__global__ __launch_bounds__(256)
void pack_w(const float* __restrict__ Wm, __bf16* __restrict__ Wf)
{
    const int gid  = blockIdx.x * 256 + threadIdx.x;  // 0..73727
    const int frag = gid >> 6;
    const int lane = gid & 63;
    const int g    = frag / NKC;
    const int kc   = frag - g * NKC;
    const float* src = Wm + (g * 16 + (lane & 15)) * Kd + kc * 32 + (lane >> 4) * 8;
    const f32x4 v0 = *(const f32x4*)src;
    const f32x4 v1 = *(const f32x4*)(src + 4);
    bf16x8 h;
    #pragma unroll
    for (int e = 0; e < 4; ++e) { h[e] = (__bf16)v0[e]; h[4 + e] = (__bf16)v1[e]; }
    *(bf16x8*)(Wf + (size_t)gid * 8) = h;
}

__global__ __launch_bounds__(256, 3)
void patch_embed_gemm(const float* __restrict__ x,
                      const __bf16* __restrict__ Wf,
                      const float* __restrict__ bias,
                      float* __restrict__ out)
{
    // A only: 64 x 64 bf16, 128-B rows, XOR-swizzled (8 KiB), single buffer
    __shared__ __align__(16) unsigned char ldsA[BM * BK * 2];

    // XCD-chunked swizzle (1152 % 8 == 0 -> bijective), bm-major: the 2
    // blocks sharing an A-panel are id-adjacent -> concurrent on one XCD.
    const int h  = blockIdx.x;
    const int l  = (h & 7) * (NBLK / 8) + (h >> 3);
    const int bm = l >> 1;
    const int bn = l & 1;

    const int tid  = threadIdx.x;
    const int lane = tid & 63;
    const int wc   = tid >> 6;   // 0..3 -> 96-col strip
    const int fr   = lane & 15;
    const int kg   = lane >> 4;

    // ---- A staging map: rows r0 + 16*it (it=0..3), chunk q
    const int q    = tid & 15;
    const int r0   = tid >> 4;
    const int px   = (q & 3) * 4;
    const int pyo  = q >> 2;
    unsigned char* const ldsA_w = ldsA + r0 * 128 + ((q * 8) ^ ((r0 & 7) << 4));

    int arow[4];
    #pragma unroll
    for (int it = 0; it < 4; ++it) {
        const int m  = bm * BM + r0 + it * 16;
        const int b  = m / Lp;
        const int li = m - b * Lp;
        const int gy = li / GWp;
        const int gx = li - gy * GWp;
        arow[it] = b * (Cch * Him * Wim) + (gy * PB) * Wim + gx * PB;
    }

    // ---- B fragment base: col-groups g = bn*24 + wc*6 + fj, k-chunk t*2+kk
    const __bf16* const wfw = Wf + (size_t)(bn * 24 + wc * 6) * NKC * 512 + lane * 8;

    f32x4 pa[4];

    auto load_A = [&](int t) {
        const int c   = t >> 2;
        const int pyb = (t & 3) * 4;
        const float* xs = x + c * (Him * Wim) + (pyb + pyo) * Wim + px;
        #pragma unroll
        for (int it = 0; it < 4; ++it)
            pa[it] = *(const f32x4*)(xs + arow[it]);
    };

    auto store_A = [&]() {
        #pragma unroll
        for (int it = 0; it < 4; ++it) {
            bf16x4 ha;
            #pragma unroll
            for (int e = 0; e < 4; ++e) ha[e] = (__bf16)pa[it][e];
            *(bf16x4*)(ldsA_w + it * 2048) = ha;   // 16 rows * 128 B
        }
    };

    f32x4 acc[4][6];
    #pragma unroll
    for (int i = 0; i < 4; ++i)
        #pragma unroll
        for (int j = 0; j < 6; ++j)
            acc[i][j] = f32x4{0.f, 0.f, 0.f, 0.f};

    const int arowb = fr * 128;
    const int sw    = (fr & 7) << 4;

    auto compute = [&](int t) {
        #pragma unroll
        for (int kk = 0; kk < 2; ++kk) {
            // 6 B fragments straight from L2 (coalesced 1024-B frags)
            bf16x8 br[6];
            #pragma unroll
            for (int fj = 0; fj < 6; ++fj)
                br[fj] = *(const bf16x8*)(wfw + (fj * NKC + t * 2 + kk) * 512);
            const int kb = (kk * 64 + kg * 16) ^ sw;   // bits 4-6 only
            #pragma unroll
            for (int fi = 0; fi < 4; ++fi) {
                const bf16x8 ar = *(const bf16x8*)(ldsA + arowb + fi * 2048 + kb);
                #pragma unroll
                for (int fj = 0; fj < 6; ++fj)
                    acc[fi][fj] = __builtin_amdgcn_mfma_f32_16x16x32_bf16(
                        ar, br[fj], acc[fi][fj], 0, 0, 0);
            }
        }
    };

    // ---- main loop: single A buffer, 2 barriers/K-step, issue-early loads
    load_A(0);
    for (int t = 0; t < NT; ++t) {
        __syncthreads();               // all reads of tile t-1 done
        store_A();                     // cvt + ds_write A(t)
        __syncthreads();               // A(t) visible
        if (t + 1 < NT) load_A(t + 1); // in flight under compute(t)
        compute(t);
    }

    // epilogue: C/D layout col = lane&15, row = (lane>>4)*4 + j
    const int orow0 = bm * BM;
    const int ocol0 = bn * BN + wc * 96;
    #pragma unroll
    for (int fj = 0; fj < 6; ++fj) {
        const int col = ocol0 + fj * 16 + fr;
        const float bv = bias[col];
        #pragma unroll
        for (int fi = 0; fi < 4; ++fi) {
            const int row = orow0 + fi * 16 + kg * 4;
            #pragma unroll
            for (int j = 0; j < 4; ++j)
                out[(row + j) * Nd + col] = acc[fi][fj][j] + bv;
        }
    }
}

} // namespace

extern "C" void kernel_launch(void* const* d_in, const int* in_sizes, int n_in,
                              void* d_out, int out_size, void* d_ws, size_t ws_size,
                              hipStream_t stream)
{
    (void)in_sizes; (void)n_in; (void)out_size; (void)ws_size;
    const float* x  = (const float*)d_in[0];
    const float* Wm = (const float*)d_in[1];
    const float* bs = (const float*)d_in[2];
    float* outp = (float*)d_out;
    __bf16* Wf = (__bf16*)d_ws;   // 768*768*2 B, fragment-ordered

    pack_w<<<dim3(Kd * Nd / (256 * 8)), dim3(256), 0, stream>>>(Wm, Wf);
    patch_embed_gemm<<<dim3(NBLK), dim3(256), 0, stream>>>(x, Wf, bs, outp);
}